// Round 4
// baseline (133.835 us; speedup 1.0000x reference)
//
#include <hip/hip_runtime.h>
#include <hip/hip_bf16.h>
#include <math.h>

#define N 8192
#define D 64
#define INVT 20.0f
#define EPS 1e-6f
// sqrt(20/ln2): gram(Z) = 20*log2(e)*cos, so exp2(gram) = e^{20 cos}
#define ZSCALE 5.3715835f
#define STRIP 8

typedef __attribute__((ext_vector_type(8))) short bf16x8;
typedef __attribute__((ext_vector_type(4))) float f32x4;

#if __has_builtin(__builtin_amdgcn_exp2f)
#define EXP2F(x) __builtin_amdgcn_exp2f(x)
#else
#define EXP2F(x) exp2f(x)
#endif

// ---------------- Kernel 1: normalize -> scaled bf16 Z, exact diag logit,
//                  zero part[] / lacc / cnt ----------------
__global__ __launch_bounds__(256) void prep_kernel(
    const float* __restrict__ A, const float* __restrict__ P,
    __hip_bfloat16* __restrict__ Zn, float* __restrict__ diag20,
    float* __restrict__ part, float* __restrict__ lacc, unsigned* __restrict__ cnt) {
    if (blockIdx.x < 64) part[blockIdx.x * 256 + threadIdx.x] = 0.0f;
    else if (blockIdx.x == 64 && threadIdx.x == 0) { *lacc = 0.0f; *cnt = 0u; }

    int lane = threadIdx.x & 63;
    int wave = threadIdx.x >> 6;
    int row  = blockIdx.x * 4 + wave;
    float a = A[row * D + lane];
    float p = P[row * D + lane];
    float sa = a * a, sp = p * p, dp = a * p;
    #pragma unroll
    for (int off = 1; off < 64; off <<= 1) {
        sa += __shfl_xor(sa, off, 64);
        sp += __shfl_xor(sp, off, 64);
        dp += __shfl_xor(dp, off, 64);
    }
    float na  = sqrtf(sa);
    float npn = sqrtf(sp);
    Zn[row * D + lane]       = __float2bfloat16(a * (ZSCALE / na));
    Zn[(N + row) * D + lane] = __float2bfloat16(p * (ZSCALE / npn));
    if (lane == 0)
        diag20[row] = (dp / fmaxf(na * npn, EPS)) * INVT;
}

// ---------------- Kernel 2: full-gram row strips, MFMA bf16, row sums only ----
// grid = (16 strips, 128 tile-rows). Block = 4 waves; wave (wr,wc) owns the
// 64x64 subtile; A-frags (rows of bi) loaded ONCE and held in VGPRs; loop over
// 8 bj tiles with row-sum accumulation in registers. One barrier; 128 atomic
// lanes per block (262k total vs 4.2M in R3 -> kills the fabric-RMW stall).
__global__ __launch_bounds__(256) void tiles_kernel(
    const __hip_bfloat16* __restrict__ Zn, float* __restrict__ part) {
    __shared__ float rs[4][16][68];    // wave-local transpose; 2-way banks max
    __shared__ float merged[2][128];   // cross-wave (wc) merge

    const int bi  = blockIdx.y;
    const int bj0 = blockIdx.x * STRIP;
    const int tid = threadIdx.x;
    const int lane = tid & 63, w = tid >> 6;
    const int wr = w >> 1, wc = w & 1;
    const int ln = lane & 15, q = lane >> 4;

    const bf16x8* Zf = (const bf16x8*)Zn;   // 8 x 16B units per 64-elem row

    // A fragments: rows bi*128 + wr*64 + ii*16 + ln, both K-chunks; held in regs
    bf16x8 af[4][2];
    {
        const int abase = (bi * 128 + wr * 64 + ln) * 8 + q;
        #pragma unroll
        for (int ii = 0; ii < 4; ++ii)
            #pragma unroll
            for (int kc = 0; kc < 2; ++kc)
                af[ii][kc] = Zf[abase + ii * 128 + kc * 4];
    }

    f32x4 rsum[4] = {};   // per-lane row partials (rows ii*16 + q*4 + r)

    int bbase = (bj0 * 128 + wc * 64 + ln) * 8 + q;
    for (int t = 0; t < STRIP; ++t) {
        const int bj = bj0 + t;
        bf16x8 bv[4][2];
        #pragma unroll
        for (int jj = 0; jj < 4; ++jj)
            #pragma unroll
            for (int kc = 0; kc < 2; ++kc)
                bv[jj][kc] = Zf[bbase + jj * 128 + kc * 4];
        bbase += 128 * 8;

        f32x4 acc[4][4] = {};
        #pragma unroll
        for (int kc = 0; kc < 2; ++kc)
            #pragma unroll
            for (int ii = 0; ii < 4; ++ii)
                #pragma unroll
                for (int jj = 0; jj < 4; ++jj)
                    acc[ii][jj] = __builtin_amdgcn_mfma_f32_16x16x32_bf16(
                        af[ii][kc], bv[jj][kc], acc[ii][jj], 0, 0, 0);

        // exp2(gram) = e^{20 cos}; zero true-diagonal elements (== ref's -e^{1/T})
        const bool dtile = (bj == bi) && (wr == wc);
        #pragma unroll
        for (int ii = 0; ii < 4; ++ii)
            #pragma unroll
            for (int jj = 0; jj < 4; ++jj) {
                f32x4 e;
                #pragma unroll
                for (int r = 0; r < 4; ++r) e[r] = EXP2F(acc[ii][jj][r]);
                if (dtile && (ii == jj)) {
                    #pragma unroll
                    for (int r = 0; r < 4; ++r)
                        if (ln == q * 4 + r) e[r] = 0.0f;
                }
                rsum[ii] += e;
            }
    }

    // wave-local LDS transpose-reduce across the 16 ln lanes (no barrier)
    #pragma unroll
    for (int ii = 0; ii < 4; ++ii)
        *(f32x4*)&rs[w][ln][ii * 16 + q * 4] = rsum[ii];
    float rowsum = 0.0f;
    #pragma unroll
    for (int l = 0; l < 16; ++l) rowsum += rs[w][l][lane];  // stride-1, conflict-free

    merged[wc][wr * 64 + lane] = rowsum;
    __syncthreads();
    if (tid < 128)
        atomicAdd(part + bi * 128 + tid, merged[0][tid] + merged[1][tid]);
}

// ---------------- Kernel 3: per-row loss + reduce + last-block finalize ------
__global__ __launch_bounds__(256) void loss_kernel(
    const float* __restrict__ part, const float* __restrict__ diag20,
    float* __restrict__ lacc, unsigned* __restrict__ cnt, float* __restrict__ out) {
    int i = blockIdx.x * 256 + threadIdx.x;
    float v = logf(part[i] + part[N + i]) - diag20[i];
    #pragma unroll
    for (int off = 32; off > 0; off >>= 1) v += __shfl_down(v, off, 64);
    __shared__ float wsm[4];
    int lane = threadIdx.x & 63, wv = threadIdx.x >> 6;
    if (lane == 0) wsm[wv] = v;
    __syncthreads();
    if (threadIdx.x == 0) {
        atomicAdd(lacc, wsm[0] + wsm[1] + wsm[2] + wsm[3]);
        __threadfence();
        unsigned old = atomicAdd(cnt, 1u);
        if (old == (N / 256 - 1)) {
            float tot = atomicAdd(lacc, 0.0f);
            out[0] = tot * (1.0f / (float)N);
        }
    }
}

// ---------------- launch ----------------
extern "C" void kernel_launch(void* const* d_in, const int* in_sizes, int n_in,
                              void* d_out, int out_size, void* d_ws, size_t ws_size,
                              hipStream_t stream) {
    const float* A = (const float*)d_in[0];
    const float* P = (const float*)d_in[1];

    __hip_bfloat16* Zn = (__hip_bfloat16*)d_ws;                 // 2N*64 bf16 = 2 MiB
    float* part   = (float*)((char*)d_ws + 2u * N * D * sizeof(__hip_bfloat16));
    float* diag20 = part + 2 * N;
    float* lacc   = diag20 + N;
    unsigned* cnt = (unsigned*)(lacc + 1);

    prep_kernel<<<N / 4, 256, 0, stream>>>(A, P, Zn, diag20, part, lacc, cnt);

    dim3 grid(128 / STRIP, 128);   // 16 strips x 128 tile-rows = 2048 blocks
    tiles_kernel<<<grid, 256, 0, stream>>>(Zn, part);

    loss_kernel<<<N / 256, 256, 0, stream>>>(part, diag20, lacc, cnt, (float*)d_out);
}

// Round 6
// 126.507 us; speedup vs baseline: 1.0579x; 1.0579x over previous
//
#include <hip/hip_runtime.h>
#include <hip/hip_bf16.h>
#include <math.h>

#define N 8192
#define D 64
#define INVT 20.0f
#define EPS 1e-6f
// sqrt(20/ln2): gram(Z) = 20*log2(e)*cos, so exp2(gram) = e^{20 cos}
#define ZSCALE 5.3715835f
#define NSTRIP 8
#define TPS 16            // tiles per strip = 128 / NSTRIP

typedef __attribute__((ext_vector_type(8))) short bf16x8;
typedef __attribute__((ext_vector_type(4))) float f32x4;

#if __has_builtin(__builtin_amdgcn_exp2f)
#define EXP2F(x) __builtin_amdgcn_exp2f(x)
#else
#define EXP2F(x) exp2f(x)
#endif

// Z layout (fragment order): G-row R, element l stored at bf16 index
//   ( (R>>4)*128 + (l>>5)*64 + ((l>>3)&3)*16 + (R&15) )*8 + (l&7)
// so the MFMA fragment load for 16-row group g, K-chunk kc is the fully
// contiguous 1 KB wave load  Zf[g*128 + kc*64 + lane]  (lane = q*16+ln holds
// row g*16+ln, elems kc*32 + q*8 .. +7 — exactly the 16x16x32 A/B layout).

// ---------------- Kernel 1: normalize -> scaled bf16 Z (fragment order) ------
__global__ __launch_bounds__(256) void prep_kernel(
    const float* __restrict__ A, const float* __restrict__ P,
    __hip_bfloat16* __restrict__ Zn, float* __restrict__ diag20,
    float* __restrict__ lacc, unsigned* __restrict__ cnt) {
    if (blockIdx.x == 0 && threadIdx.x == 0) { *lacc = 0.0f; *cnt = 0u; }

    const int lane = threadIdx.x & 63;   // element index l
    const int w    = threadIdx.x >> 6;
    const int r    = blockIdx.x * 4 + w; // A/P row
    const int u    = lane >> 3, sub = lane & 7;
    const int upos = (u >> 2) * 64 + (u & 3) * 16;   // kc*64 + q*16

    float a = A[r * D + lane];
    float p = P[r * D + lane];
    float sa = a * a, sp = p * p, dp = a * p;
    #pragma unroll
    for (int off = 1; off < 64; off <<= 1) {
        sa += __shfl_xor(sa, off, 64);
        sp += __shfl_xor(sp, off, 64);
        dp += __shfl_xor(dp, off, 64);
    }
    float na  = sqrtf(sa);
    float npn = sqrtf(sp);
    {   // A-row R = r
        int g = r >> 4, l2 = r & 15;
        Zn[(g * 128 + upos + l2) * 8 + sub] = __float2bfloat16(a * (ZSCALE / na));
    }
    {   // P-row R = N + r
        int R = N + r; int g = R >> 4, l2 = R & 15;
        Zn[(g * 128 + upos + l2) * 8 + sub] = __float2bfloat16(p * (ZSCALE / npn));
    }
    if (lane == 0)
        diag20[r] = (dp / fmaxf(na * npn, EPS)) * INVT;
}

// ---------------- Kernel 2: full-gram row strips, contiguous fragment loads --
// grid = (NSTRIP, 128 tile-rows). Block = 4 waves; wave (wr,wc) owns a 64x64
// subtile; A-frags held in VGPRs for the whole strip; B-frags double-buffered.
// Row sums accumulate in registers; one LDS transpose + merge; part2 slice
// written exactly once (no atomics, no zero-init).
__global__ __launch_bounds__(256) void tiles_kernel(
    const __hip_bfloat16* __restrict__ Zn, float* __restrict__ part2) {
    __shared__ float rs[4][16][68];    // wave-local transpose; 2-way banks max
    __shared__ float merged[2][128];

    const int s  = blockIdx.x;          // strip
    const int tr = blockIdx.y;          // tile row 0..127
    const int tid = threadIdx.x;
    const int lane = tid & 63, w = tid >> 6;
    const int wr = w >> 1, wc = w & 1;
    const int ln = lane & 15, q = lane >> 4;
    const bf16x8* Zf = (const bf16x8*)Zn;

    // A fragments: groups tr*8 + wr*4 + ii, both K-chunks (contiguous 1KB loads)
    bf16x8 af[4][2];
    #pragma unroll
    for (int ii = 0; ii < 4; ++ii) {
        int g = tr * 8 + wr * 4 + ii;
        #pragma unroll
        for (int kc = 0; kc < 2; ++kc)
            af[ii][kc] = Zf[g * 128 + kc * 64 + lane];
    }

    f32x4 rsum[4] = {};
    const int bj0 = s * TPS;
    bf16x8 bv0[4][2], bv1[4][2];

    #pragma unroll
    for (int jj = 0; jj < 4; ++jj) {
        int g = bj0 * 8 + wc * 4 + jj;
        #pragma unroll
        for (int kc = 0; kc < 2; ++kc)
            bv0[jj][kc] = Zf[g * 128 + kc * 64 + lane];
    }

    for (int t = 0; t < TPS; ++t) {
        bf16x8 (&cur)[4][2] = (t & 1) ? bv1 : bv0;
        bf16x8 (&nxt)[4][2] = (t & 1) ? bv0 : bv1;
        if (t + 1 < TPS) {
            #pragma unroll
            for (int jj = 0; jj < 4; ++jj) {
                int g = (bj0 + t + 1) * 8 + wc * 4 + jj;
                #pragma unroll
                for (int kc = 0; kc < 2; ++kc)
                    nxt[jj][kc] = Zf[g * 128 + kc * 64 + lane];
            }
        }

        f32x4 acc[4][4] = {};
        #pragma unroll
        for (int kc = 0; kc < 2; ++kc)
            #pragma unroll
            for (int ii = 0; ii < 4; ++ii)
                #pragma unroll
                for (int jj = 0; jj < 4; ++jj)
                    acc[ii][jj] = __builtin_amdgcn_mfma_f32_16x16x32_bf16(
                        af[ii][kc], cur[jj][kc], acc[ii][jj], 0, 0, 0);

        // exp2(gram) = e^{20 cos}; zero true-diagonal elems (== ref's -e^{1/T})
        const bool dtile = ((bj0 + t) == tr) && (wr == wc);
        #pragma unroll
        for (int ii = 0; ii < 4; ++ii)
            #pragma unroll
            for (int jj = 0; jj < 4; ++jj) {
                f32x4 e;
                #pragma unroll
                for (int r = 0; r < 4; ++r) e[r] = EXP2F(acc[ii][jj][r]);
                if (dtile && (ii == jj)) {
                    #pragma unroll
                    for (int r = 0; r < 4; ++r)
                        if (ln == q * 4 + r) e[r] = 0.0f;
                }
                rsum[ii] += e;
            }
    }

    // wave-local LDS transpose-reduce across the 16 ln lanes (no barrier)
    #pragma unroll
    for (int ii = 0; ii < 4; ++ii)
        *(f32x4*)&rs[w][ln][ii * 16 + q * 4] = rsum[ii];
    float rowsum = 0.0f;
    #pragma unroll
    for (int l = 0; l < 16; ++l) rowsum += rs[w][l][lane];  // stride-1, no conflicts
    merged[wc][wr * 64 + lane] = rowsum;
    __syncthreads();
    if (tid < 128)
        part2[s * (2 * N) + tr * 128 + tid] = merged[0][tid] + merged[1][tid];
}

// ---------------- Kernel 3: per-row loss + reduce + last-block finalize ------
__global__ __launch_bounds__(256) void loss_kernel(
    const float* __restrict__ part2, const float* __restrict__ diag20,
    float* __restrict__ lacc, unsigned* __restrict__ cnt, float* __restrict__ out) {
    int i = blockIdx.x * 256 + threadIdx.x;
    float partition = 0.0f;
    #pragma unroll
    for (int s = 0; s < NSTRIP; ++s)
        partition += part2[s * (2 * N) + i] + part2[s * (2 * N) + N + i];
    float v = logf(partition) - diag20[i];
    #pragma unroll
    for (int off = 32; off > 0; off >>= 1) v += __shfl_down(v, off, 64);
    __shared__ float wsm[4];
    int lane = threadIdx.x & 63, wv = threadIdx.x >> 6;
    if (lane == 0) wsm[wv] = v;
    __syncthreads();
    if (threadIdx.x == 0) {
        atomicAdd(lacc, wsm[0] + wsm[1] + wsm[2] + wsm[3]);
        __threadfence();
        unsigned old = atomicAdd(cnt, 1u);
        if (old == (N / 256 - 1)) {
            float tot = atomicAdd(lacc, 0.0f);
            out[0] = tot * (1.0f / (float)N);
        }
    }
}

// ---------------- launch ----------------
extern "C" void kernel_launch(void* const* d_in, const int* in_sizes, int n_in,
                              void* d_out, int out_size, void* d_ws, size_t ws_size,
                              hipStream_t stream) {
    const float* A = (const float*)d_in[0];
    const float* P = (const float*)d_in[1];

    __hip_bfloat16* Zn = (__hip_bfloat16*)d_ws;                 // 2N*64 bf16 = 2 MiB
    float* diag20 = (float*)((char*)d_ws + 2u * N * D * sizeof(__hip_bfloat16));
    float* part2  = diag20 + N;          // NSTRIP * 2N floats = 512 KiB
    float* lacc   = part2 + NSTRIP * 2 * N;
    unsigned* cnt = (unsigned*)(lacc + 1);

    prep_kernel<<<N / 4, 256, 0, stream>>>(A, P, Zn, diag20, lacc, cnt);

    dim3 grid(NSTRIP, 128);   // 1024 blocks
    tiles_kernel<<<grid, 256, 0, stream>>>(Zn, part2);

    loss_kernel<<<N / 256, 256, 0, stream>>>(part2, diag20, lacc, cnt, (float*)d_out);
}

// Round 7
// 103.932 us; speedup vs baseline: 1.2877x; 1.2172x over previous
//
#include <hip/hip_runtime.h>
#include <hip/hip_bf16.h>
#include <math.h>

#define N 8192
#define D 64
#define INVT 20.0f
#define EPS 1e-6f
// sqrt(20/ln2): gram(Z) = 20*log2(e)*cos, so exp2(gram) = e^{20 cos}
#define ZSCALE 5.3715835f

typedef __attribute__((ext_vector_type(8))) short bf16x8;
typedef __attribute__((ext_vector_type(4))) float f32x4;

#if __has_builtin(__builtin_amdgcn_exp2f)
#define EXP2F(x) __builtin_amdgcn_exp2f(x)
#else
#define EXP2F(x) exp2f(x)
#endif

// Z layout (fragment order): G-row R, element l stored at bf16 index
//   ( (R>>4)*128 + (l>>5)*64 + ((l>>3)&3)*16 + (R&15) )*8 + (l&7)
// so the MFMA fragment load for 16-row group g, K-chunk kc is the fully
// contiguous 1 KB wave load  Zf[g*128 + kc*64 + lane].

// ---------------- Kernel 1: normalize -> scaled bf16 Z (fragment order),
//                  zero part[] / lacc / cnt ----------------
__global__ __launch_bounds__(256) void prep_kernel(
    const float* __restrict__ A, const float* __restrict__ P,
    __hip_bfloat16* __restrict__ Zn, float* __restrict__ diag20,
    float* __restrict__ part, float* __restrict__ lacc, unsigned* __restrict__ cnt) {
    if (blockIdx.x < 64) part[blockIdx.x * 256 + threadIdx.x] = 0.0f;
    else if (blockIdx.x == 64 && threadIdx.x == 0) { *lacc = 0.0f; *cnt = 0u; }

    const int lane = threadIdx.x & 63;   // element index l
    const int w    = threadIdx.x >> 6;
    const int r    = blockIdx.x * 4 + w; // A/P row
    const int u    = lane >> 3, sub = lane & 7;
    const int upos = (u >> 2) * 64 + (u & 3) * 16;   // kc*64 + q*16

    float a = A[r * D + lane];
    float p = P[r * D + lane];
    float sa = a * a, sp = p * p, dp = a * p;
    #pragma unroll
    for (int off = 1; off < 64; off <<= 1) {
        sa += __shfl_xor(sa, off, 64);
        sp += __shfl_xor(sp, off, 64);
        dp += __shfl_xor(dp, off, 64);
    }
    float na  = sqrtf(sa);
    float npn = sqrtf(sp);
    {   // A-row R = r
        int g = r >> 4, l2 = r & 15;
        Zn[(g * 128 + upos + l2) * 8 + sub] = __float2bfloat16(a * (ZSCALE / na));
    }
    {   // P-row R = N + r
        int R = N + r; int g = R >> 4, l2 = R & 15;
        Zn[(g * 128 + upos + l2) * 8 + sub] = __float2bfloat16(p * (ZSCALE / npn));
    }
    if (lane == 0)
        diag20[r] = (dp / fmaxf(na * npn, EPS)) * INVT;
}

// ---------------- Kernel 2: upper-triangular tiles, contiguous frag loads ----
// 8256 blocks, one 128x128 tile each (0 <= bi <= bj < 128). Wave (wr,wc) owns
// a 64x64 subtile. All fragments live in VGPRs (one contiguous 1KB wave load
// each). Row sums -> rows of tile-row bi; col sums (by symmetry) -> rows of
// tile bj (skipped when bi==bj). LDS-merged, 256 atomic lanes per block.
__global__ __launch_bounds__(256) void tiles_kernel(
    const __hip_bfloat16* __restrict__ Zn, float* __restrict__ part) {
    __shared__ float rs[4][16][68];     // wave-local transpose; 2-way banks max
    __shared__ float merged[2][128];    // row merge over wc
    __shared__ float cmerged[2][2][64]; // col merge over wr: [wr][wc][col]

    // unrank blockIdx.x -> (bi, bj), 0 <= bi <= bj < 128
    int t = (int)blockIdx.x;
    int b = (int)((257.0f - sqrtf(66049.0f - 8.0f * (float)t)) * 0.5f);
    while (b * (257 - b) / 2 > t) --b;
    while ((b + 1) * (256 - b) / 2 <= t) ++b;
    const int bi = b;
    const int bj = b + (t - b * (257 - b) / 2);
    const bool diag = (bi == bj);

    const int tid = threadIdx.x;
    const int lane = tid & 63, w = tid >> 6;
    const int wr = w >> 1, wc = w & 1;
    const int ln = lane & 15, q = lane >> 4;
    const bf16x8* Zf = (const bf16x8*)Zn;

    // fragments: contiguous 1KB wave loads, all up-front
    bf16x8 af[4][2], bv[4][2];
    #pragma unroll
    for (int ii = 0; ii < 4; ++ii) {
        int ga = bi * 8 + wr * 4 + ii;
        int gb = bj * 8 + wc * 4 + ii;
        #pragma unroll
        for (int kc = 0; kc < 2; ++kc) {
            af[ii][kc] = Zf[ga * 128 + kc * 64 + lane];
            bv[ii][kc] = Zf[gb * 128 + kc * 64 + lane];
        }
    }

    f32x4 acc[4][4] = {};
    #pragma unroll
    for (int kc = 0; kc < 2; ++kc)
        #pragma unroll
        for (int ii = 0; ii < 4; ++ii)
            #pragma unroll
            for (int jj = 0; jj < 4; ++jj)
                acc[ii][jj] = __builtin_amdgcn_mfma_f32_16x16x32_bf16(
                    af[ii][kc], bv[jj][kc], acc[ii][jj], 0, 0, 0);

    // epilogue: exp2(gram) = e^{20 cos}; zero true-diag elems (== -e^{1/T})
    const bool dwave = diag && (wr == wc);
    f32x4 rsumv[4] = {};
    f32x4 csumv[4] = {};
    #pragma unroll
    for (int ii = 0; ii < 4; ++ii)
        #pragma unroll
        for (int jj = 0; jj < 4; ++jj) {
            f32x4 e;
            #pragma unroll
            for (int r = 0; r < 4; ++r) e[r] = EXP2F(acc[ii][jj][r]);
            if (dwave && (ii == jj)) {
                #pragma unroll
                for (int r = 0; r < 4; ++r)
                    if (ln == q * 4 + r) e[r] = 0.0f;
            }
            rsumv[ii] += e;
            csumv[jj] += e;
        }

    // ---- row sums: wave-local LDS transpose (no barrier), merge over wc ----
    #pragma unroll
    for (int ii = 0; ii < 4; ++ii)
        *(f32x4*)&rs[w][ln][ii * 16 + q * 4] = rsumv[ii];
    float rowsum = 0.0f;
    #pragma unroll
    for (int l = 0; l < 16; ++l) rowsum += rs[w][l][lane];  // stride-1, no conflicts
    merged[wc][wr * 64 + lane] = rowsum;

    // ---- col sums: horizontal 4->1, butterfly over q, stash per (wr,wc) ----
    float cs0 = (csumv[0][0] + csumv[0][1]) + (csumv[0][2] + csumv[0][3]);
    float cs1 = (csumv[1][0] + csumv[1][1]) + (csumv[1][2] + csumv[1][3]);
    float cs2 = (csumv[2][0] + csumv[2][1]) + (csumv[2][2] + csumv[2][3]);
    float cs3 = (csumv[3][0] + csumv[3][1]) + (csumv[3][2] + csumv[3][3]);
    cs0 += __shfl_xor(cs0, 16, 64); cs0 += __shfl_xor(cs0, 32, 64);
    cs1 += __shfl_xor(cs1, 16, 64); cs1 += __shfl_xor(cs1, 32, 64);
    cs2 += __shfl_xor(cs2, 16, 64); cs2 += __shfl_xor(cs2, 32, 64);
    cs3 += __shfl_xor(cs3, 16, 64); cs3 += __shfl_xor(cs3, 32, 64);
    float cval = (q == 0) ? cs0 : (q == 1) ? cs1 : (q == 2) ? cs2 : cs3;
    cmerged[wr][wc][q * 16 + ln] = cval;   // lanes (q,ln) cover all 64 cols once
    __syncthreads();

    if (tid < 128) {
        atomicAdd(part + bi * 128 + tid, merged[0][tid] + merged[1][tid]);
    } else if (!diag) {
        int col = tid - 128;               // 0..127 ; wc = col>>6
        atomicAdd(part + bj * 128 + col,
                  cmerged[0][col >> 6][col & 63] + cmerged[1][col >> 6][col & 63]);
    }
}

// ---------------- Kernel 3: per-row loss + reduce + last-block finalize ------
__global__ __launch_bounds__(256) void loss_kernel(
    const float* __restrict__ part, const float* __restrict__ diag20,
    float* __restrict__ lacc, unsigned* __restrict__ cnt, float* __restrict__ out) {
    int i = blockIdx.x * 256 + threadIdx.x;
    float v = logf(part[i] + part[N + i]) - diag20[i];
    #pragma unroll
    for (int off = 32; off > 0; off >>= 1) v += __shfl_down(v, off, 64);
    __shared__ float wsm[4];
    int lane = threadIdx.x & 63, wv = threadIdx.x >> 6;
    if (lane == 0) wsm[wv] = v;
    __syncthreads();
    if (threadIdx.x == 0) {
        atomicAdd(lacc, wsm[0] + wsm[1] + wsm[2] + wsm[3]);
        __threadfence();
        unsigned old = atomicAdd(cnt, 1u);
        if (old == (N / 256 - 1)) {
            float tot = atomicAdd(lacc, 0.0f);
            out[0] = tot * (1.0f / (float)N);
        }
    }
}

// ---------------- launch ----------------
extern "C" void kernel_launch(void* const* d_in, const int* in_sizes, int n_in,
                              void* d_out, int out_size, void* d_ws, size_t ws_size,
                              hipStream_t stream) {
    const float* A = (const float*)d_in[0];
    const float* P = (const float*)d_in[1];

    __hip_bfloat16* Zn = (__hip_bfloat16*)d_ws;                 // 2N*64 bf16 = 2 MiB
    float* diag20 = (float*)((char*)d_ws + 2u * N * D * sizeof(__hip_bfloat16));
    float* part   = diag20 + N;          // 2N floats, atomic-accumulated
    float* lacc   = part + 2 * N;
    unsigned* cnt = (unsigned*)(lacc + 1);

    prep_kernel<<<N / 4, 256, 0, stream>>>(A, P, Zn, diag20, part, lacc, cnt);

    const int nblocks = 128 * 129 / 2;   // 8256 upper-triangular 128-tiles
    tiles_kernel<<<nblocks, 256, 0, stream>>>(Zn, part);

    loss_kernel<<<N / 256, 256, 0, stream>>>(part, diag20, lacc, cnt, (float*)d_out);
}

// Round 8
// 93.053 us; speedup vs baseline: 1.4383x; 1.1169x over previous
//
#include <hip/hip_runtime.h>
#include <hip/hip_bf16.h>
#include <math.h>

#define N 8192
#define D 64
#define INVT 20.0f
#define EPS 1e-6f
// sqrt(20/ln2): gram(Z) = 20*log2(e)*cos, so exp2(gram) = e^{20 cos}
#define ZSCALE 5.3715835f

typedef __attribute__((ext_vector_type(8))) short bf16x8;
typedef __attribute__((ext_vector_type(4))) float f32x4;

#if __has_builtin(__builtin_amdgcn_exp2f)
#define EXP2F(x) __builtin_amdgcn_exp2f(x)
#else
#define EXP2F(x) exp2f(x)
#endif

// Z layout (fragment order): G-row R, element l stored at bf16 index
//   ( (R>>4)*128 + (l>>5)*64 + ((l>>3)&3)*16 + (R&15) )*8 + (l&7)
// so the MFMA fragment load for 16-row group g, K-chunk kc is the fully
// contiguous 1 KB wave load  Zf[g*128 + kc*64 + lane].

// ---------------- Kernel 1: normalize -> scaled bf16 Z (fragment order),
//                  zero part[] / lacc / cnt ----------------
__global__ __launch_bounds__(256) void prep_kernel(
    const float* __restrict__ A, const float* __restrict__ P,
    __hip_bfloat16* __restrict__ Zn, float* __restrict__ diag20,
    float* __restrict__ part, float* __restrict__ lacc, unsigned* __restrict__ cnt) {
    if (blockIdx.x < 64) part[blockIdx.x * 256 + threadIdx.x] = 0.0f;
    else if (blockIdx.x == 64 && threadIdx.x == 0) { *lacc = 0.0f; *cnt = 0u; }

    const int lane = threadIdx.x & 63;   // element index l
    const int w    = threadIdx.x >> 6;
    const int r    = blockIdx.x * 4 + w; // A/P row
    const int u    = lane >> 3, sub = lane & 7;
    const int upos = (u >> 2) * 64 + (u & 3) * 16;   // kc*64 + q*16

    float a = A[r * D + lane];
    float p = P[r * D + lane];
    float sa = a * a, sp = p * p, dp = a * p;
    #pragma unroll
    for (int off = 1; off < 64; off <<= 1) {
        sa += __shfl_xor(sa, off, 64);
        sp += __shfl_xor(sp, off, 64);
        dp += __shfl_xor(dp, off, 64);
    }
    float na  = sqrtf(sa);
    float npn = sqrtf(sp);
    {   // A-row R = r
        int g = r >> 4, l2 = r & 15;
        Zn[(g * 128 + upos + l2) * 8 + sub] = __float2bfloat16(a * (ZSCALE / na));
    }
    {   // P-row R = N + r
        int R = N + r; int g = R >> 4, l2 = R & 15;
        Zn[(g * 128 + upos + l2) * 8 + sub] = __float2bfloat16(p * (ZSCALE / npn));
    }
    if (lane == 0)
        diag20[r] = (dp / fmaxf(na * npn, EPS)) * INVT;
}

// ---------------- Kernel 2: upper-triangular tiles, low-AGPR epilogue --------
// 8256 blocks, one 128x128 tile each (0 <= bi <= bj < 128). Wave (wr,wc) owns
// a 64x64 subtile. ii-outer / jj-inner with only acc[4] (16 AGPRs) live: each
// 16-row stripe is MFMA'd then immediately exp'd + accumulated, so residency
// rises from 3 to 4+ waves/SIMD (acc[4][4] previously held 64 AGPRs).
__global__ __launch_bounds__(256, 4) void tiles_kernel(
    const __hip_bfloat16* __restrict__ Zn, float* __restrict__ part) {
    __shared__ float rs[4][16][68];     // wave-local transpose; 2-way banks max
    __shared__ float merged[2][128];    // row merge over wc
    __shared__ float cmerged[2][2][64]; // col merge over wr: [wr][wc][col]

    // unrank blockIdx.x -> (bi, bj), 0 <= bi <= bj < 128
    int t = (int)blockIdx.x;
    int b = (int)((257.0f - sqrtf(66049.0f - 8.0f * (float)t)) * 0.5f);
    while (b * (257 - b) / 2 > t) --b;
    while ((b + 1) * (256 - b) / 2 <= t) ++b;
    const int bi = b;
    const int bj = b + (t - b * (257 - b) / 2);
    const bool diag = (bi == bj);

    const int tid = threadIdx.x;
    const int lane = tid & 63, w = tid >> 6;
    const int wr = w >> 1, wc = w & 1;
    const int ln = lane & 15, q = lane >> 4;
    const bf16x8* Zf = (const bf16x8*)Zn;

    // fragments: contiguous 1KB wave loads, all up-front
    bf16x8 af[4][2], bv[4][2];
    #pragma unroll
    for (int ii = 0; ii < 4; ++ii) {
        int ga = bi * 8 + wr * 4 + ii;
        int gb = bj * 8 + wc * 4 + ii;
        #pragma unroll
        for (int kc = 0; kc < 2; ++kc) {
            af[ii][kc] = Zf[ga * 128 + kc * 64 + lane];
            bv[ii][kc] = Zf[gb * 128 + kc * 64 + lane];
        }
    }

    const bool dwave = diag && (wr == wc);
    const f32x4 zero = {0.0f, 0.0f, 0.0f, 0.0f};
    f32x4 csumv[4] = {};

    #pragma unroll
    for (int ii = 0; ii < 4; ++ii) {
        // 16-row stripe: 8 MFMA into 4 accumulators (16 AGPRs live)
        f32x4 acc[4];
        #pragma unroll
        for (int jj = 0; jj < 4; ++jj)
            acc[jj] = __builtin_amdgcn_mfma_f32_16x16x32_bf16(
                af[ii][0], bv[jj][0], zero, 0, 0, 0);
        #pragma unroll
        for (int jj = 0; jj < 4; ++jj)
            acc[jj] = __builtin_amdgcn_mfma_f32_16x16x32_bf16(
                af[ii][1], bv[jj][1], acc[jj], 0, 0, 0);

        // immediate epilogue: exp2(gram) = e^{20 cos}; zero true-diag elems
        f32x4 rsum_ii = {};
        #pragma unroll
        for (int jj = 0; jj < 4; ++jj) {
            f32x4 e;
            #pragma unroll
            for (int r = 0; r < 4; ++r) e[r] = EXP2F(acc[jj][r]);
            if (dwave && (ii == jj)) {
                #pragma unroll
                for (int r = 0; r < 4; ++r)
                    if (ln == q * 4 + r) e[r] = 0.0f;
            }
            rsum_ii += e;
            csumv[jj] += e;
        }
        // stash this stripe's row partials straight into the transpose slot
        *(f32x4*)&rs[w][ln][ii * 16 + q * 4] = rsum_ii;
    }

    // ---- row sums: wave-local transpose read (no barrier needed) ----
    float rowsum = 0.0f;
    #pragma unroll
    for (int l = 0; l < 16; ++l) rowsum += rs[w][l][lane];  // stride-1, no conflicts
    merged[wc][wr * 64 + lane] = rowsum;

    // ---- col sums: horizontal 4->1, butterfly over q, stash per (wr,wc) ----
    float cs0 = (csumv[0][0] + csumv[0][1]) + (csumv[0][2] + csumv[0][3]);
    float cs1 = (csumv[1][0] + csumv[1][1]) + (csumv[1][2] + csumv[1][3]);
    float cs2 = (csumv[2][0] + csumv[2][1]) + (csumv[2][2] + csumv[2][3]);
    float cs3 = (csumv[3][0] + csumv[3][1]) + (csumv[3][2] + csumv[3][3]);
    cs0 += __shfl_xor(cs0, 16, 64); cs0 += __shfl_xor(cs0, 32, 64);
    cs1 += __shfl_xor(cs1, 16, 64); cs1 += __shfl_xor(cs1, 32, 64);
    cs2 += __shfl_xor(cs2, 16, 64); cs2 += __shfl_xor(cs2, 32, 64);
    cs3 += __shfl_xor(cs3, 16, 64); cs3 += __shfl_xor(cs3, 32, 64);
    float cval = (q == 0) ? cs0 : (q == 1) ? cs1 : (q == 2) ? cs2 : cs3;
    cmerged[wr][wc][q * 16 + ln] = cval;   // lanes (q,ln) cover all 64 cols once
    __syncthreads();

    if (tid < 128) {
        atomicAdd(part + bi * 128 + tid, merged[0][tid] + merged[1][tid]);
    } else if (!diag) {
        int col = tid - 128;               // 0..127 ; wc = col>>6
        atomicAdd(part + bj * 128 + col,
                  cmerged[0][col >> 6][col & 63] + cmerged[1][col >> 6][col & 63]);
    }
}

// ---------------- Kernel 3: per-row loss + reduce + last-block finalize ------
__global__ __launch_bounds__(256) void loss_kernel(
    const float* __restrict__ part, const float* __restrict__ diag20,
    float* __restrict__ lacc, unsigned* __restrict__ cnt, float* __restrict__ out) {
    int i = blockIdx.x * 256 + threadIdx.x;
    float v = logf(part[i] + part[N + i]) - diag20[i];
    #pragma unroll
    for (int off = 32; off > 0; off >>= 1) v += __shfl_down(v, off, 64);
    __shared__ float wsm[4];
    int lane = threadIdx.x & 63, wv = threadIdx.x >> 6;
    if (lane == 0) wsm[wv] = v;
    __syncthreads();
    if (threadIdx.x == 0) {
        atomicAdd(lacc, wsm[0] + wsm[1] + wsm[2] + wsm[3]);
        __threadfence();
        unsigned old = atomicAdd(cnt, 1u);
        if (old == (N / 256 - 1)) {
            float tot = atomicAdd(lacc, 0.0f);
            out[0] = tot * (1.0f / (float)N);
        }
    }
}

// ---------------- launch ----------------
extern "C" void kernel_launch(void* const* d_in, const int* in_sizes, int n_in,
                              void* d_out, int out_size, void* d_ws, size_t ws_size,
                              hipStream_t stream) {
    const float* A = (const float*)d_in[0];
    const float* P = (const float*)d_in[1];

    __hip_bfloat16* Zn = (__hip_bfloat16*)d_ws;                 // 2N*64 bf16 = 2 MiB
    float* diag20 = (float*)((char*)d_ws + 2u * N * D * sizeof(__hip_bfloat16));
    float* part   = diag20 + N;          // 2N floats, atomic-accumulated
    float* lacc   = part + 2 * N;
    unsigned* cnt = (unsigned*)(lacc + 1);

    prep_kernel<<<N / 4, 256, 0, stream>>>(A, P, Zn, diag20, part, lacc, cnt);

    const int nblocks = 128 * 129 / 2;   // 8256 upper-triangular 128-tiles
    tiles_kernel<<<nblocks, 256, 0, stream>>>(Zn, part);

    loss_kernel<<<N / 256, 256, 0, stream>>>(part, diag20, lacc, cnt, (float*)d_out);
}